// Round 4
// baseline (2170.755 us; speedup 1.0000x reference)
//
#include <hip/hip_runtime.h>

// CIN fused kernel, round 8: round-7 counted-vmcnt pipeline, two bugfixes.
// Round-7 failed (absmax=inf) from XPAD=38: i spans 0..38 (39 values), so
// rows aliased and the final write went OOB into bst -> garbage B-frags.
// Fix 1: XPAD=39 (LDS total 81,472 B, still 2 blocks/CU).
// Fix 2: s_barrier is NOT a compiler fence -> add sched_barrier(0) after the
// second barrier too, so the refill STAGE (global_load_lds) cannot hoist
// above it and overwrite bst[bb] while other waves still read it.
// Pipeline (T3+T4 minimum): 3 rotating 8 KB buffers staged 2 chunks ahead
// (chunk = 2 k-steps), raw s_barrier + counted s_waitcnt vmcnt(4/2/0) so
// prefetched chunks stay in flight ACROSS barriers. Refills stop at NC-4;
// tail waits keep counts exact; all control flow wave-uniform.
// All register-array indices are compile-time literals (round-3 lesson).
// GEMM: M = B*16 (m = batch*16+d), N = 128, K = i*64+j.
// Block = 256 thr (4 waves), NB = 16 batches. Wave w: batches w*4..w*4+4
// (2 m-tiles of 32 rows) x full N=128 (4 n-tiles). acc = 2x4 f32x16 (AGPR).

#define F0N 39
#define NC16 156                              // K/16 per layer
#define LAYER_HALVES (NC16 * 4 * 64 * 8)      // 319488 f16 per layer
#define XPAD 39                               // xs row stride (i spans 0..38!)

typedef _Float16 half8 __attribute__((ext_vector_type(8)));
typedef float f32x16 __attribute__((ext_vector_type(16)));

// ---- prep: swizzle filters into 32x32x16 B-fragment order, f16 ----
// fprep[l][c16][nt][lane][reg] = F_l[row(kg), nt*32 + (lane&31)],
// kg = c16*16 + (lane>>5)*8 + reg; layer0 row = i*39+j (j=kg&63), 0 if j>=39.
__global__ void prep_kernel(const float* __restrict__ f0,
                            const float* __restrict__ f1,
                            const float* __restrict__ f2,
                            _Float16* __restrict__ fprep) {
    int blk  = blockIdx.x;            // l*NC16 + c16
    int l    = blk / NC16;
    int c16  = blk - l * NC16;
    int t    = threadIdx.x;
    int nt   = t >> 6;
    int lane = t & 63;
    int hf   = lane >> 5;
    int n    = nt * 32 + (lane & 31);
    const float* f = (l == 0) ? f0 : ((l == 1) ? f1 : f2);
    half8 v;
    #pragma unroll
    for (int reg = 0; reg < 8; ++reg) {
        int kg = c16 * 16 + hf * 8 + reg;
        float x;
        if (l == 0) {
            int fi = kg >> 6, fj = kg & 63;
            x = (fj < F0N) ? f[(fi * F0N + fj) * 128 + n] : 0.0f;
        } else {
            x = f[(size_t)kg * 128 + n];
        }
        v[reg] = (_Float16)x;
    }
    *(half8*)&fprep[(size_t)l * LAYER_HALVES + (((c16 * 4 + nt) * 64 + lane) << 3)] = v;
}

// ---- LDS B-frag load: BUF runtime (LDS addressing), SLOT literal ----
#define LOAD_BF_L(BUF, SLOT)                                                  \
    half8 Bf[4];                                                              \
    {                                                                         \
        _Pragma("unroll")                                                     \
        for (int nt = 0; nt < 4; ++nt)                                        \
            Bf[nt] = *(const half8*)&bst[BUF][(SLOT) * 2048 + ((nt * 64 + lane) << 3)]; \
    }

#define DO_MFMA()                                                             \
    {                                                                         \
        _Pragma("unroll")                                                     \
        for (int mt = 0; mt < 2; ++mt)                                        \
            _Pragma("unroll")                                                 \
            for (int nt = 0; nt < 4; ++nt)                                    \
                acc[mt][nt] = __builtin_amdgcn_mfma_f32_32x32x16_f16(         \
                    Af[mt], Bf[nt], acc[mt][nt], 0, 0, 0);                    \
    }

// staged full step: B from bst[BUF] slot SLOT, hreg k-slot Q (Q, SLOT literal)
#define FULL_STEP_LS(BUF, SLOT, Q)                                            \
    do {                                                                      \
        LOAD_BF_L(BUF, SLOT);                                                 \
        half8 Af[2];                                                          \
        _Pragma("unroll")                                                     \
        for (int mt = 0; mt < 2; ++mt) Af[mt] = hreg[mt][(Q)] * xv2[mt];      \
        DO_MFMA();                                                            \
    } while (0)

// staged partial step: zero elements with j <= i (j = Q*16 + hf*8 + reg)
#define PART_STEP_LS(BUF, SLOT, Q)                                            \
    do {                                                                      \
        LOAD_BF_L(BUF, SLOT);                                                 \
        const int j0 = (Q) * 16 + hf * 8;                                     \
        half8 msk;                                                            \
        _Pragma("unroll")                                                     \
        for (int reg = 0; reg < 8; ++reg)                                     \
            msk[reg] = (j0 + reg > i) ? (_Float16)1.0f : (_Float16)0.0f;      \
        half8 Af[2];                                                          \
        _Pragma("unroll")                                                     \
        for (int mt = 0; mt < 2; ++mt) Af[mt] = hreg[mt][(Q)] * (msk * xv2[mt]); \
        DO_MFMA();                                                            \
    } while (0)

// cooperative stage of one 2-step chunk (8 KB) into bst[BUF]; S0 = step index
// 256 thr x 2 x global_load_lds_dwordx4; LDS dest = wave-uniform base + lane*16.
#define STAGE(BUF, S0)                                                        \
    do {                                                                      \
        const _Float16* gsrc = fpl + ((size_t)(S0) << 11) + (t << 3);         \
        __builtin_amdgcn_global_load_lds(                                     \
            (const __attribute__((address_space(1))) void*)gsrc,              \
            (__attribute__((address_space(3))) void*)&bst[BUF][t << 3],       \
            16, 0, 0);                                                        \
        __builtin_amdgcn_global_load_lds(                                     \
            (const __attribute__((address_space(1))) void*)(gsrc + 2048),     \
            (__attribute__((address_space(3))) void*)&bst[BUF][2048 + (t << 3)], \
            16, 0, 0);                                                        \
    } while (0)

// counted wait: only the oldest (outstanding - N) loads must retire.
#define WAITN(N) asm volatile("s_waitcnt vmcnt(" #N ")" ::: "memory")
#define BARRIER() __builtin_amdgcn_s_barrier()
#define SCHED_FENCE() __builtin_amdgcn_sched_barrier(0)

__global__ __launch_bounds__(256, 2) void cin_mfma(
    const float* __restrict__ xin,     // (B, 624) fp32
    const _Float16* __restrict__ fprep,
    const float* __restrict__ wnn,     // (256)
    const float* __restrict__ bnn,     // (1)
    float* __restrict__ out)           // (B)
{
    __shared__ _Float16 hT[16 * 16 * 72] __attribute__((aligned(16)));  // [nb][d][j pad72]
    __shared__ _Float16 xs[16 * 16 * XPAD] __attribute__((aligned(16)));// [nb][d][i], stride 39
    __shared__ _Float16 bst[3][4096] __attribute__((aligned(16)));      // B 3-buf rotation
    __shared__ float outacc[16];

    const int t     = threadIdx.x;
    const int wave  = t >> 6;
    const int lane  = t & 63;
    const int hf    = lane >> 5;     // k-half within 16-chunk
    const int lane5 = lane & 31;
    const int dl    = lane & 15;     // d for A-side
    const int bt    = lane5 >> 4;    // A-side batch within 32-row tile
    const int wb0   = wave * 4;      // wave's first batch (local)
    const int b0    = blockIdx.x * 16;

    // zero hT (j-pad must be 0: layer-0 h-runs read j up to 63)
    for (int u = t; u < 2304; u += 256) ((uint4*)hT)[u] = uint4{0, 0, 0, 0};
    if (t < 16) outacc[t] = 0.0f;
    __syncthreads();

    // stage x0 -> hT (layer-0 hidden, [nb][d][j=i]) and xs ([nb][d][i])
    for (int u = t; u < 16 * F0N; u += 256) {
        int nb = u / F0N;
        int i  = u - nb * F0N;
        const float* src = xin + (size_t)(b0 + nb) * 624 + i * 16;
        #pragma unroll
        for (int q = 0; q < 4; ++q) {
            float4 v = *(const float4*)(src + q * 4);
            int d = q * 4;
            hT[(nb * 16 + d + 0) * 72 + i] = (_Float16)v.x;
            hT[(nb * 16 + d + 1) * 72 + i] = (_Float16)v.y;
            hT[(nb * 16 + d + 2) * 72 + i] = (_Float16)v.z;
            hT[(nb * 16 + d + 3) * 72 + i] = (_Float16)v.w;
            xs[(nb * 16 + d + 0) * XPAD + i] = (_Float16)v.x;
            xs[(nb * 16 + d + 1) * XPAD + i] = (_Float16)v.y;
            xs[(nb * 16 + d + 2) * XPAD + i] = (_Float16)v.z;
            xs[(nb * 16 + d + 3) * XPAD + i] = (_Float16)v.w;
        }
    }
    __syncthreads();

    for (int layer = 0; layer < 3; ++layer) {
        const _Float16* fpl = fprep + (size_t)layer * LAYER_HALVES;

        // lane's A rows: m = lane5 -> batch wb0 + mt*2 + bt, d = dl.
        // j runs r*16 + hf*8 .. +8 for r = 0..3 -> 4 half8 per batch.
        half8 hreg[2][4];
        #pragma unroll
        for (int mt = 0; mt < 2; ++mt) {
            int base = ((wb0 + mt * 2 + bt) * 16 + dl) * 72 + hf * 8;
            #pragma unroll
            for (int r = 0; r < 4; ++r)
                hreg[mt][r] = *(const half8*)&hT[base + r * 16];
        }
        __syncthreads();   // h-regs loaded (epilogue may overwrite hT); drains all

        // prologue prefetch: chunks 0,1,2 -> bufs 0,1,2 (6 loads in flight)
        STAGE(0, 0);
        STAGE(1, 2);
        STAGE(2, 4);

        f32x16 acc[2][4];
        #pragma unroll
        for (int mt = 0; mt < 2; ++mt)
            #pragma unroll
            for (int nt = 0; nt < 4; ++nt)
                #pragma unroll
                for (int e = 0; e < 16; ++e) acc[mt][nt][e] = 0.0f;

        const int xrow0 = ((wb0 + bt) * 16 + dl) * XPAD;
        const int xrow1 = ((wb0 + 2 + bt) * 16 + dl) * XPAD;

        if (layer == 0) {
            // Sparse schedule. K = i*64+j, live j: i < j < 39.
            // chunk 2i   = (q0,q1): q0 partial i<15; q1 full i<16 / part i<31
            // chunk 2i+1 = (q2,q3): q2 full i<32 / part; q3 all-zero, unread.
            // NC = 76 chunks; refill while c <= 72; tail waits 4/2/0.
            _Float16 xv2[2];
            int bb = 0;
            for (int c = 0; c < 76; ++c) {
                const int i = c >> 1;
                xv2[0] = (_Float16)2.0f * xs[xrow0 + i];
                xv2[1] = (_Float16)2.0f * xs[xrow1 + i];
                if (c <= 73)      { WAITN(4); }
                else if (c == 74) { WAITN(2); }
                else              { WAITN(0); }
                BARRIER();
                SCHED_FENCE();   // ds_reads of bst[bb] must stay after barrier
                if ((c & 1) == 0) {
                    if (i < 15)      PART_STEP_LS(bb, 0, 0); // q0 partial
                    if (i < 16)      FULL_STEP_LS(bb, 1, 1); // q1 full
                    else if (i < 31) PART_STEP_LS(bb, 1, 1); // q1 partial
                    // i >= 31: chunk is dead but sync cadence preserved
                } else {
                    if (i < 32) FULL_STEP_LS(bb, 0, 2);      // q2 full
                    else        PART_STEP_LS(bb, 0, 2);      // q2 partial
                }
                BARRIER();
                SCHED_FENCE();   // refill STAGE must stay after barrier
                if (c <= 72) STAGE(bb, (c + 3) * 2);
                ++bb; if (bb == 3) bb = 0;
            }
        } else {
            // Dense: NC = 78 chunks; refill while c <= 74; tail waits 4/2/0.
            _Float16 xv2[2];
            int bb = 0;
            for (int c = 0; c < 78; ++c) {
                const int i = c >> 1;
                xv2[0] = xs[xrow0 + i];
                xv2[1] = xs[xrow1 + i];
                if (c <= 75)      { WAITN(4); }
                else if (c == 76) { WAITN(2); }
                else              { WAITN(0); }
                BARRIER();
                SCHED_FENCE();
                if ((c & 1) == 0) {
                    FULL_STEP_LS(bb, 0, 0);
                    FULL_STEP_LS(bb, 1, 1);
                } else {
                    FULL_STEP_LS(bb, 0, 2);
                    FULL_STEP_LS(bb, 1, 3);
                }
                BARRIER();
                SCHED_FENCE();
                if (c <= 74) STAGE(bb, (c + 3) * 2);
                ++bb; if (bb == 3) bb = 0;
            }
        }

        // ---- epilogue ---- (outstanding vmcnt = 0 here: tail waited 0)
        // C/D layout: col n = nt*32 + lane5; row = (reg&3) + 8*(reg>>2) + 4*hf;
        // batch_in_tile = reg>>3, d = (reg&3) + 8*((reg>>2)&1) + 4*hf.
        const int catbase = (layer == 2) ? 128 : ((layer == 0) ? -64 : 0);
        #pragma unroll
        for (int mt = 0; mt < 2; ++mt) {
            const int nb0 = wb0 + mt * 2;
            float cm0 = 0.0f, cm1 = 0.0f;
            #pragma unroll
            for (int nt = 0; nt < 4; ++nt) {
                float r[16];
                #pragma unroll
                for (int reg = 0; reg < 16; ++reg)
                    r[reg] = fmaxf(acc[mt][nt][reg], 0.0f);
                if (layer < 2 && nt < 2) {         // next hidden: cols 0..63
                    const int j = nt * 32 + lane5;
                    #pragma unroll
                    for (int reg = 0; reg < 16; ++reg) {
                        int nb = nb0 + (reg >> 3);
                        int d  = (reg & 3) + 8 * ((reg >> 2) & 1) + 4 * hf;
                        hT[(nb * 16 + d) * 72 + j] = (_Float16)r[reg];
                    }
                }
                if (layer == 2 || nt >= 2) {       // direct-out readout
                    const float w = 1.0f + wnn[catbase + nt * 32 + lane5];
                    float s0 = ((r[0] + r[1]) + (r[2] + r[3])) +
                               ((r[4] + r[5]) + (r[6] + r[7]));
                    float s1 = ((r[8] + r[9]) + (r[10] + r[11])) +
                               ((r[12] + r[13]) + (r[14] + r[15]));
                    s0 += __shfl_xor(s0, 32, 64);  // combine hf halves (full d-sum)
                    s1 += __shfl_xor(s1, 32, 64);
                    cm0 = fmaf(s0, w, cm0);
                    cm1 = fmaf(s1, w, cm1);
                }
            }
            #pragma unroll
            for (int sh = 16; sh >= 1; sh >>= 1) {
                cm0 += __shfl_xor(cm0, sh, 64);
                cm1 += __shfl_xor(cm1, sh, 64);
            }
            if (lane == 0) {
                atomicAdd(&outacc[nb0], cm0);
                atomicAdd(&outacc[nb0 + 1], cm1);
            }
        }
        __syncthreads();   // hT(next hidden) + outacc visible
    }

    if (t < 16) out[b0 + t] = outacc[t] + bnn[0];
}

extern "C" void kernel_launch(void* const* d_in, const int* in_sizes, int n_in,
                              void* d_out, int out_size, void* d_ws, size_t ws_size,
                              hipStream_t stream) {
    const float* xin = (const float*)d_in[0];
    const float* f0g = (const float*)d_in[1];
    const float* f1g = (const float*)d_in[2];
    const float* f2g = (const float*)d_in[3];
    const float* wnn = (const float*)d_in[4];
    const float* bnn = (const float*)d_in[5];
    float* out = (float*)d_out;
    _Float16* fprep = (_Float16*)d_ws;   // 3 * 319488 * 2 B = 1.83 MB

    prep_kernel<<<3 * NC16, 256, 0, stream>>>(f0g, f1g, f2g, fprep);

    const int B = in_sizes[0] / 624;     // 8192
    cin_mfma<<<B / 16, 256, 0, stream>>>(xin, fprep, wnn, bnn, out);
}

// Round 6
// 600.107 us; speedup vs baseline: 3.6173x; 3.6173x over previous
//
#include <hip/hip_runtime.h>

// CIN fused kernel, round 9 (resubmit; broker timeout last round).
// Round-8 counters (2171us, WRITE 7.6GB, FETCH 2.6GB, MfmaUtil 4%) = acc
// spilling to scratch inside the K-loop (58 KB/thread written). Deltas vs
// non-spilling round 6 were (a) runtime bb buffer index, (b) sched_barrier(0)
// fences freezing the pre-RA scheduler. Round 9 keeps the 3-buffer depth-2
// counted-vmcnt pipeline but:
//   - literal buffer indices via 6-chunk unroll (78 = 6*13; BUF = OFF%3,
//     slot parity = OFF&1, all compile-time)
//   - no sched_barrier; barriers are asm volatile("s_barrier" ::: "memory"),
//     whose memory clobber orders ds_read / global_load_lds across them at
//     the compiler level without freezing register scheduling
//   - layer 0 runs the same 78-chunk cadence (chunks 76/77 dead, guarded;
//     fprep layer-0 rows with j>=39 are zero)
// vmcnt discipline: only STAGE issues VMEM in-loop; outacc atomics are LDS;
// layer-end __syncthreads drains to zero. Steady WAITN(4) keeps 2 chunks in
// flight across barriers; tail waits 4/2/0; refills stop at chunk 74.
// All register-array indices are compile-time literals (round-3 lesson).
// GEMM: M = B*16 (m = batch*16+d), N = 128, K = i*64+j.
// Block = 256 thr (4 waves), NB = 16 batches. Wave w: batches w*4..w*4+4
// (2 m-tiles of 32 rows) x full N=128 (4 n-tiles). acc = 2x4 f32x16 (AGPR).

#define F0N 39
#define NC16 156                              // K/16 per layer
#define LAYER_HALVES (NC16 * 4 * 64 * 8)      // 319488 f16 per layer
#define XPAD 39                               // xs row stride (i spans 0..38)

typedef _Float16 half8 __attribute__((ext_vector_type(8)));
typedef float f32x16 __attribute__((ext_vector_type(16)));

// ---- prep: swizzle filters into 32x32x16 B-fragment order, f16 ----
// fprep[l][c16][nt][lane][reg] = F_l[row(kg), nt*32 + (lane&31)],
// kg = c16*16 + (lane>>5)*8 + reg; layer0 row = i*39+j (j=kg&63), 0 if j>=39.
__global__ void prep_kernel(const float* __restrict__ f0,
                            const float* __restrict__ f1,
                            const float* __restrict__ f2,
                            _Float16* __restrict__ fprep) {
    int blk  = blockIdx.x;            // l*NC16 + c16
    int l    = blk / NC16;
    int c16  = blk - l * NC16;
    int t    = threadIdx.x;
    int nt   = t >> 6;
    int lane = t & 63;
    int hf   = lane >> 5;
    int n    = nt * 32 + (lane & 31);
    const float* f = (l == 0) ? f0 : ((l == 1) ? f1 : f2);
    half8 v;
    #pragma unroll
    for (int reg = 0; reg < 8; ++reg) {
        int kg = c16 * 16 + hf * 8 + reg;
        float x;
        if (l == 0) {
            int fi = kg >> 6, fj = kg & 63;
            x = (fj < F0N) ? f[(fi * F0N + fj) * 128 + n] : 0.0f;
        } else {
            x = f[(size_t)kg * 128 + n];
        }
        v[reg] = (_Float16)x;
    }
    *(half8*)&fprep[(size_t)l * LAYER_HALVES + (((c16 * 4 + nt) * 64 + lane) << 3)] = v;
}

// ---- LDS B-frag load: BUF and SLOT are compile-time literals ----
#define LOAD_BF_L(BUF, SLOT)                                                  \
    half8 Bf[4];                                                              \
    {                                                                         \
        _Pragma("unroll")                                                     \
        for (int nt = 0; nt < 4; ++nt)                                        \
            Bf[nt] = *(const half8*)&bst[BUF][(SLOT) * 2048 + ((nt * 64 + lane) << 3)]; \
    }

#define DO_MFMA()                                                             \
    {                                                                         \
        _Pragma("unroll")                                                     \
        for (int mt = 0; mt < 2; ++mt)                                        \
            _Pragma("unroll")                                                 \
            for (int nt = 0; nt < 4; ++nt)                                    \
                acc[mt][nt] = __builtin_amdgcn_mfma_f32_32x32x16_f16(         \
                    Af[mt], Bf[nt], acc[mt][nt], 0, 0, 0);                    \
    }

// staged full step: B from bst[BUF] slot SLOT, hreg k-slot Q (all literals)
#define FULL_STEP_LS(BUF, SLOT, Q)                                            \
    do {                                                                      \
        LOAD_BF_L(BUF, SLOT);                                                 \
        half8 Af[2];                                                          \
        _Pragma("unroll")                                                     \
        for (int mt = 0; mt < 2; ++mt) Af[mt] = hreg[mt][(Q)] * xv2[mt];      \
        DO_MFMA();                                                            \
    } while (0)

// staged partial step: zero elements with j <= i (j = Q*16 + hf*8 + reg)
#define PART_STEP_LS(BUF, SLOT, Q)                                            \
    do {                                                                      \
        LOAD_BF_L(BUF, SLOT);                                                 \
        const int j0 = (Q) * 16 + hf * 8;                                     \
        half8 msk;                                                            \
        _Pragma("unroll")                                                     \
        for (int reg = 0; reg < 8; ++reg)                                     \
            msk[reg] = (j0 + reg > i) ? (_Float16)1.0f : (_Float16)0.0f;      \
        half8 Af[2];                                                          \
        _Pragma("unroll")                                                     \
        for (int mt = 0; mt < 2; ++mt) Af[mt] = hreg[mt][(Q)] * (msk * xv2[mt]); \
        DO_MFMA();                                                            \
    } while (0)

// cooperative stage of one 2-step chunk (8 KB) into bst[BUF]; S0 = step index
// 256 thr x 2 x global_load_lds_dwordx4; LDS dest = wave-uniform base + lane*16.
#define STAGE(BUF, S0)                                                        \
    do {                                                                      \
        const _Float16* gsrc = fpl + ((size_t)(S0) << 11) + (t << 3);         \
        __builtin_amdgcn_global_load_lds(                                     \
            (const __attribute__((address_space(1))) void*)gsrc,              \
            (__attribute__((address_space(3))) void*)&bst[BUF][t << 3],       \
            16, 0, 0);                                                        \
        __builtin_amdgcn_global_load_lds(                                     \
            (const __attribute__((address_space(1))) void*)(gsrc + 2048),     \
            (__attribute__((address_space(3))) void*)&bst[BUF][2048 + (t << 3)], \
            16, 0, 0);                                                        \
    } while (0)

// counted wait: only the oldest (outstanding - N) loads must retire.
#define WAITN(N) asm volatile("s_waitcnt vmcnt(" #N ")" ::: "memory")
// barrier with compiler memory ordering (s_barrier alone is not a fence)
#define BARRIER_M() asm volatile("s_barrier" ::: "memory")

// one dense chunk; OFF in 0..5 literal, BUF = OFF%3 literal, parity = OFF&1
#define CHUNK_DENSE(OFF, BUF)                                                 \
    do {                                                                      \
        const int c = cc + (OFF);                                             \
        const int i = c >> 1;                                                 \
        _Float16 xv2[2];                                                      \
        xv2[0] = xs[xrow0 + i];                                               \
        xv2[1] = xs[xrow1 + i];                                               \
        if (c <= 75)      { WAITN(4); }                                       \
        else if (c == 76) { WAITN(2); }                                       \
        else              { WAITN(0); }                                       \
        BARRIER_M();                                                          \
        if (((OFF) & 1) == 0) {                                               \
            FULL_STEP_LS(BUF, 0, 0);                                          \
            FULL_STEP_LS(BUF, 1, 1);                                          \
        } else {                                                              \
            FULL_STEP_LS(BUF, 0, 2);                                          \
            FULL_STEP_LS(BUF, 1, 3);                                          \
        }                                                                     \
        BARRIER_M();                                                          \
        if (c <= 74) STAGE(BUF, (c + 3) * 2);                                 \
    } while (0)

// one sparse (layer-0) chunk. K = i*64+j, live j: i < j < 39.
// even chunk = (q0,q1): q0 partial i<15; q1 full i<16 / partial i<31.
// odd  chunk = (q2,q3): q2 full i<32 / partial i<38; q3 zero, unread.
#define CHUNK_SPARSE(OFF, BUF)                                                \
    do {                                                                      \
        const int c = cc + (OFF);                                             \
        const int i = c >> 1;                                                 \
        _Float16 xv2[2];                                                      \
        xv2[0] = (_Float16)2.0f * xs[xrow0 + i];                              \
        xv2[1] = (_Float16)2.0f * xs[xrow1 + i];                              \
        if (c <= 75)      { WAITN(4); }                                       \
        else if (c == 76) { WAITN(2); }                                       \
        else              { WAITN(0); }                                       \
        BARRIER_M();                                                          \
        if (((OFF) & 1) == 0) {                                               \
            if (i < 15)      PART_STEP_LS(BUF, 0, 0);                         \
            if (i < 16)      FULL_STEP_LS(BUF, 1, 1);                         \
            else if (i < 31) PART_STEP_LS(BUF, 1, 1);                         \
        } else {                                                              \
            if (i < 32)      FULL_STEP_LS(BUF, 0, 2);                         \
            else if (i < 38) PART_STEP_LS(BUF, 0, 2);                         \
        }                                                                     \
        BARRIER_M();                                                          \
        if (c <= 74) STAGE(BUF, (c + 3) * 2);                                 \
    } while (0)

__global__ __launch_bounds__(256, 2) void cin_mfma(
    const float* __restrict__ xin,     // (B, 624) fp32
    const _Float16* __restrict__ fprep,
    const float* __restrict__ wnn,     // (256)
    const float* __restrict__ bnn,     // (1)
    float* __restrict__ out)           // (B)
{
    __shared__ _Float16 hT[16 * 16 * 72] __attribute__((aligned(16)));  // [nb][d][j pad72]
    __shared__ _Float16 xs[16 * 16 * XPAD] __attribute__((aligned(16)));// [nb][d][i], stride 39
    __shared__ _Float16 bst[3][4096] __attribute__((aligned(16)));      // B 3-buf rotation
    __shared__ float outacc[16];

    const int t     = threadIdx.x;
    const int wave  = t >> 6;
    const int lane  = t & 63;
    const int hf    = lane >> 5;     // k-half within 16-chunk
    const int lane5 = lane & 31;
    const int dl    = lane & 15;     // d for A-side
    const int bt    = lane5 >> 4;    // A-side batch within 32-row tile
    const int wb0   = wave * 4;      // wave's first batch (local)
    const int b0    = blockIdx.x * 16;

    // zero hT (j-pad must be 0: layer-0 h-runs read j up to 63)
    for (int u = t; u < 2304; u += 256) ((uint4*)hT)[u] = uint4{0, 0, 0, 0};
    if (t < 16) outacc[t] = 0.0f;
    __syncthreads();

    // stage x0 -> hT (layer-0 hidden, [nb][d][j=i]) and xs ([nb][d][i])
    for (int u = t; u < 16 * F0N; u += 256) {
        int nb = u / F0N;
        int i  = u - nb * F0N;
        const float* src = xin + (size_t)(b0 + nb) * 624 + i * 16;
        #pragma unroll
        for (int q = 0; q < 4; ++q) {
            float4 v = *(const float4*)(src + q * 4);
            int d = q * 4;
            hT[(nb * 16 + d + 0) * 72 + i] = (_Float16)v.x;
            hT[(nb * 16 + d + 1) * 72 + i] = (_Float16)v.y;
            hT[(nb * 16 + d + 2) * 72 + i] = (_Float16)v.z;
            hT[(nb * 16 + d + 3) * 72 + i] = (_Float16)v.w;
            xs[(nb * 16 + d + 0) * XPAD + i] = (_Float16)v.x;
            xs[(nb * 16 + d + 1) * XPAD + i] = (_Float16)v.y;
            xs[(nb * 16 + d + 2) * XPAD + i] = (_Float16)v.z;
            xs[(nb * 16 + d + 3) * XPAD + i] = (_Float16)v.w;
        }
    }
    __syncthreads();

    for (int layer = 0; layer < 3; ++layer) {
        const _Float16* fpl = fprep + (size_t)layer * LAYER_HALVES;

        // lane's A rows: m = lane5 -> batch wb0 + mt*2 + bt, d = dl.
        // j runs r*16 + hf*8 .. +8 for r = 0..3 -> 4 half8 per batch.
        half8 hreg[2][4];
        #pragma unroll
        for (int mt = 0; mt < 2; ++mt) {
            int base = ((wb0 + mt * 2 + bt) * 16 + dl) * 72 + hf * 8;
            #pragma unroll
            for (int r = 0; r < 4; ++r)
                hreg[mt][r] = *(const half8*)&hT[base + r * 16];
        }
        __syncthreads();   // h-regs loaded (epilogue may overwrite hT); drains all

        // prologue prefetch: chunks 0,1,2 -> bufs 0,1,2 (6 loads in flight)
        STAGE(0, 0);
        STAGE(1, 2);
        STAGE(2, 4);

        f32x16 acc[2][4];
        #pragma unroll
        for (int mt = 0; mt < 2; ++mt)
            #pragma unroll
            for (int nt = 0; nt < 4; ++nt)
                #pragma unroll
                for (int e = 0; e < 16; ++e) acc[mt][nt][e] = 0.0f;

        const int xrow0 = ((wb0 + bt) * 16 + dl) * XPAD;
        const int xrow1 = ((wb0 + 2 + bt) * 16 + dl) * XPAD;

        // 78 chunks = 13 x 6; buffer ids and slot parity are literals.
        if (layer == 0) {
            for (int cc = 0; cc < 78; cc += 6) {
                CHUNK_SPARSE(0, 0);
                CHUNK_SPARSE(1, 1);
                CHUNK_SPARSE(2, 2);
                CHUNK_SPARSE(3, 0);
                CHUNK_SPARSE(4, 1);
                CHUNK_SPARSE(5, 2);
            }
        } else {
            for (int cc = 0; cc < 78; cc += 6) {
                CHUNK_DENSE(0, 0);
                CHUNK_DENSE(1, 1);
                CHUNK_DENSE(2, 2);
                CHUNK_DENSE(3, 0);
                CHUNK_DENSE(4, 1);
                CHUNK_DENSE(5, 2);
            }
        }

        // ---- epilogue ---- (vmcnt = 0 here: final chunk waited 0)
        // C/D layout: col n = nt*32 + lane5; row = (reg&3) + 8*(reg>>2) + 4*hf;
        // batch_in_tile = reg>>3, d = (reg&3) + 8*((reg>>2)&1) + 4*hf.
        const int catbase = (layer == 2) ? 128 : ((layer == 0) ? -64 : 0);
        #pragma unroll
        for (int mt = 0; mt < 2; ++mt) {
            const int nb0 = wb0 + mt * 2;
            float cm0 = 0.0f, cm1 = 0.0f;
            #pragma unroll
            for (int nt = 0; nt < 4; ++nt) {
                float r[16];
                #pragma unroll
                for (int reg = 0; reg < 16; ++reg)
                    r[reg] = fmaxf(acc[mt][nt][reg], 0.0f);
                if (layer < 2 && nt < 2) {         // next hidden: cols 0..63
                    const int j = nt * 32 + lane5;
                    #pragma unroll
                    for (int reg = 0; reg < 16; ++reg) {
                        int nb = nb0 + (reg >> 3);
                        int d  = (reg & 3) + 8 * ((reg >> 2) & 1) + 4 * hf;
                        hT[(nb * 16 + d) * 72 + j] = (_Float16)r[reg];
                    }
                }
                if (layer == 2 || nt >= 2) {       // direct-out readout
                    const float w = 1.0f + wnn[catbase + nt * 32 + lane5];
                    float s0 = ((r[0] + r[1]) + (r[2] + r[3])) +
                               ((r[4] + r[5]) + (r[6] + r[7]));
                    float s1 = ((r[8] + r[9]) + (r[10] + r[11])) +
                               ((r[12] + r[13]) + (r[14] + r[15]));
                    s0 += __shfl_xor(s0, 32, 64);  // combine hf halves (full d-sum)
                    s1 += __shfl_xor(s1, 32, 64);
                    cm0 = fmaf(s0, w, cm0);
                    cm1 = fmaf(s1, w, cm1);
                }
            }
            #pragma unroll
            for (int sh = 16; sh >= 1; sh >>= 1) {
                cm0 += __shfl_xor(cm0, sh, 64);
                cm1 += __shfl_xor(cm1, sh, 64);
            }
            if (lane == 0) {
                atomicAdd(&outacc[nb0], cm0);
                atomicAdd(&outacc[nb0 + 1], cm1);
            }
        }
        __syncthreads();   // hT(next hidden) + outacc visible; drains vmcnt
    }

    if (t < 16) out[b0 + t] = outacc[t] + bnn[0];
}

extern "C" void kernel_launch(void* const* d_in, const int* in_sizes, int n_in,
                              void* d_out, int out_size, void* d_ws, size_t ws_size,
                              hipStream_t stream) {
    const float* xin = (const float*)d_in[0];
    const float* f0g = (const float*)d_in[1];
    const float* f1g = (const float*)d_in[2];
    const float* f2g = (const float*)d_in[3];
    const float* wnn = (const float*)d_in[4];
    const float* bnn = (const float*)d_in[5];
    float* out = (float*)d_out;
    _Float16* fprep = (_Float16*)d_ws;   // 3 * 319488 * 2 B = 1.83 MB

    prep_kernel<<<3 * NC16, 256, 0, stream>>>(f0g, f1g, f2g, fprep);

    const int B = in_sizes[0] / 624;     // 8192
    cin_mfma<<<B / 16, 256, 0, stream>>>(xin, fprep, wnn, bnn, out);
}

// Round 7
// 255.589 us; speedup vs baseline: 8.4932x; 2.3479x over previous
//
#include <hip/hip_runtime.h>

// CIN fused kernel, round 10: revert to round-4 barrier-free streaming,
// double the batch tile (NB=32, 512 thr, 1 block/CU).
// Post-mortem r4/r6/r9: every LDS-staging variant lost to the barrier-free
// per-wave B-stream (253 vs 375/600 us). r4's speed comes from L1 serving
// intra-block B reuse (4 waves, identical addresses): pure-L2 model predicts
// ~440us, L1-reuse model predicts ~253us = measured. So the lever is MORE
// L1-shared reuse: 8 waves in one block stream identical Bf addresses ->
// L2 demand halves (8->4 KB/step/CU ~ 72 cyc < 128 cyc MFMA issue) ->
// MFMA-issue-bound. K-loop has ZERO barriers: the compiler freely pipelines
// the Bf global loads (this is what made r4 fast; r7-r9's explicit sync
// defeated it and added scratch spill, WRITE 1GB).
// Per-wave code identical to r4 (acc 2x4 f32x16, 256-reg budget at
// launch_bounds(512,2)); only block geometry and epilogue bounds change.
// GEMM: M = B*16 (m = batch*16+d), N = 128, K = i*64+j (layer-0 sparse).
// Block = 512 thr (8 waves), NB = 32 batches. Wave w: batches w*4..w*4+4
// (2 m-tiles of 32 rows) x full N=128 (4 n-tiles). acc = 2x4 f32x16 (AGPR).

#define F0N 39
#define NB  32                                // batches per block
#define NC16 156                              // K/16 per layer
#define LAYER_HALVES (NC16 * 4 * 64 * 8)      // 319488 f16 per layer

typedef _Float16 half8 __attribute__((ext_vector_type(8)));
typedef float f32x16 __attribute__((ext_vector_type(16)));

// ---- prep: swizzle filters into 32x32x16 B-fragment order, f16 ----
// fprep[l][c16][nt][lane][reg] = F_l[row(kg), nt*32 + (lane&31)],
// kg = c16*16 + (lane>>5)*8 + reg; layer0 row = i*39+j (j=kg&63), 0 if j>=39.
__global__ void prep_kernel(const float* __restrict__ f0,
                            const float* __restrict__ f1,
                            const float* __restrict__ f2,
                            _Float16* __restrict__ fprep) {
    int blk  = blockIdx.x;            // l*NC16 + c16
    int l    = blk / NC16;
    int c16  = blk - l * NC16;
    int t    = threadIdx.x;
    int nt   = t >> 6;
    int lane = t & 63;
    int hf   = lane >> 5;
    int n    = nt * 32 + (lane & 31);
    const float* f = (l == 0) ? f0 : ((l == 1) ? f1 : f2);
    half8 v;
    #pragma unroll
    for (int reg = 0; reg < 8; ++reg) {
        int kg = c16 * 16 + hf * 8 + reg;
        float x;
        if (l == 0) {
            int fi = kg >> 6, fj = kg & 63;
            x = (fj < F0N) ? f[(fi * F0N + fj) * 128 + n] : 0.0f;
        } else {
            x = f[(size_t)kg * 128 + n];
        }
        v[reg] = (_Float16)x;
    }
    *(half8*)&fprep[(size_t)l * LAYER_HALVES + (((c16 * 4 + nt) * 64 + lane) << 3)] = v;
}

// One K=16 step, Q is a LITERAL (keeps hreg indexing static).
#define LOAD_BF(C16)                                                          \
    half8 Bf[4];                                                              \
    {                                                                         \
        _Pragma("unroll")                                                     \
        for (int nt = 0; nt < 4; ++nt)                                        \
            Bf[nt] = *(const half8*)(fpl + ((((C16) * 4 + nt) * 64 + lane) << 3)); \
    }

#define DO_MFMA()                                                             \
    {                                                                         \
        _Pragma("unroll")                                                     \
        for (int mt = 0; mt < 2; ++mt)                                        \
            _Pragma("unroll")                                                 \
            for (int nt = 0; nt < 4; ++nt)                                    \
                acc[mt][nt] = __builtin_amdgcn_mfma_f32_32x32x16_f16(         \
                    Af[mt], Bf[nt], acc[mt][nt], 0, 0, 0);                    \
    }

#define FULL_STEP(Q)                                                          \
    do {                                                                      \
        LOAD_BF(i * 4 + (Q));                                                 \
        half8 Af[2];                                                          \
        _Pragma("unroll")                                                     \
        for (int mt = 0; mt < 2; ++mt) Af[mt] = hreg[mt][(Q)] * xv2[mt];      \
        DO_MFMA();                                                            \
    } while (0)

// partial: zero elements with j <= i (j = Q*16 + hf*8 + reg)
#define PART_STEP(Q)                                                          \
    do {                                                                      \
        LOAD_BF(i * 4 + (Q));                                                 \
        const int j0 = (Q) * 16 + hf * 8;                                     \
        half8 msk;                                                            \
        _Pragma("unroll")                                                     \
        for (int reg = 0; reg < 8; ++reg)                                     \
            msk[reg] = (j0 + reg > i) ? (_Float16)1.0f : (_Float16)0.0f;      \
        half8 Af[2];                                                          \
        _Pragma("unroll")                                                     \
        for (int mt = 0; mt < 2; ++mt) Af[mt] = hreg[mt][(Q)] * (msk * xv2[mt]); \
        DO_MFMA();                                                            \
    } while (0)

__global__ __launch_bounds__(512, 2) void cin_mfma(
    const float* __restrict__ xin,     // (B, 624) fp32
    const _Float16* __restrict__ fprep,
    const float* __restrict__ wnn,     // (256)
    const float* __restrict__ bnn,     // (1)
    float* __restrict__ out)           // (B)
{
    __shared__ _Float16 hT[NB * 16 * 72] __attribute__((aligned(16)));  // [nb][d][j pad72]
    __shared__ _Float16 xs[NB * 16 * 40] __attribute__((aligned(16)));  // [nb][d][i pad40]
    __shared__ float outacc[NB];

    const int t     = threadIdx.x;
    const int wave  = t >> 6;
    const int lane  = t & 63;
    const int hf    = lane >> 5;     // k-half within 16-chunk
    const int lane5 = lane & 31;
    const int dl    = lane & 15;     // d for A-side
    const int bt    = lane5 >> 4;    // A-side batch within 32-row tile
    const int wb0   = wave * 4;      // wave's first batch (local, 0..28)
    const int b0    = blockIdx.x * NB;

    // zero hT (j-pad must be 0: layer-0 h-runs read j up to 63)
    for (int u = t; u < NB * 16 * 72 / 8; u += 512) ((uint4*)hT)[u] = uint4{0, 0, 0, 0};
    if (t < NB) outacc[t] = 0.0f;
    __syncthreads();

    // stage x0 -> hT (layer-0 hidden, [nb][d][j=i]) and xs ([nb][d][i])
    for (int u = t; u < NB * F0N; u += 512) {
        int nb = u / F0N;
        int i  = u - nb * F0N;
        const float* src = xin + (size_t)(b0 + nb) * 624 + i * 16;
        #pragma unroll
        for (int q = 0; q < 4; ++q) {
            float4 v = *(const float4*)(src + q * 4);
            int d = q * 4;
            hT[(nb * 16 + d + 0) * 72 + i] = (_Float16)v.x;
            hT[(nb * 16 + d + 1) * 72 + i] = (_Float16)v.y;
            hT[(nb * 16 + d + 2) * 72 + i] = (_Float16)v.z;
            hT[(nb * 16 + d + 3) * 72 + i] = (_Float16)v.w;
            xs[(nb * 16 + d + 0) * 40 + i] = (_Float16)v.x;
            xs[(nb * 16 + d + 1) * 40 + i] = (_Float16)v.y;
            xs[(nb * 16 + d + 2) * 40 + i] = (_Float16)v.z;
            xs[(nb * 16 + d + 3) * 40 + i] = (_Float16)v.w;
        }
    }
    __syncthreads();

    for (int layer = 0; layer < 3; ++layer) {
        // lane's A rows: m = lane5 -> batch wb0 + mt*2 + bt, d = dl.
        // j runs r*16 + hf*8 .. +8 for r = 0..3 -> 4 half8 per batch.
        half8 hreg[2][4];
        #pragma unroll
        for (int mt = 0; mt < 2; ++mt) {
            int base = ((wb0 + mt * 2 + bt) * 16 + dl) * 72 + hf * 8;
            #pragma unroll
            for (int r = 0; r < 4; ++r)
                hreg[mt][r] = *(const half8*)&hT[base + r * 16];
        }
        __syncthreads();   // h-regs loaded before epilogue may overwrite hT

        f32x16 acc[2][4];
        #pragma unroll
        for (int mt = 0; mt < 2; ++mt)
            #pragma unroll
            for (int nt = 0; nt < 4; ++nt)
                #pragma unroll
                for (int e = 0; e < 16; ++e) acc[mt][nt][e] = 0.0f;

        const _Float16* fpl = fprep + (size_t)layer * LAYER_HALVES;
        const int xrow0 = ((wb0 + bt) * 16 + dl) * 40;
        const int xrow1 = ((wb0 + 2 + bt) * 16 + dl) * 40;

        if (layer == 0) {
            // K = i*64+j, j>i, j<39 (j>=39 -> zero filter, harmless).
            _Float16 xv2[2];
            // i in [0,16): q0 partial (skip i==15), q1 full, q2 full
            for (int i = 0; i < 16; ++i) {
                xv2[0] = (_Float16)2.0f * xs[xrow0 + i];
                xv2[1] = (_Float16)2.0f * xs[xrow1 + i];
                if (i < 15) PART_STEP(0);
                FULL_STEP(1);
                FULL_STEP(2);
            }
            // i in [16,32): q1 partial (skip i==31), q2 full
            for (int i = 16; i < 32; ++i) {
                xv2[0] = (_Float16)2.0f * xs[xrow0 + i];
                xv2[1] = (_Float16)2.0f * xs[xrow1 + i];
                if (i < 31) PART_STEP(1);
                FULL_STEP(2);
            }
            // i in [32,38): q2 partial
            for (int i = 32; i < 38; ++i) {
                xv2[0] = (_Float16)2.0f * xs[xrow0 + i];
                xv2[1] = (_Float16)2.0f * xs[xrow1 + i];
                PART_STEP(2);
            }
        } else {
            _Float16 xv2[2];
            for (int i = 0; i < F0N; ++i) {
                xv2[0] = xs[xrow0 + i];
                xv2[1] = xs[xrow1 + i];
                FULL_STEP(0);
                FULL_STEP(1);
                FULL_STEP(2);
                FULL_STEP(3);
            }
        }

        // ---- epilogue ----
        // C/D layout: col n = nt*32 + lane5; row = (reg&3) + 8*(reg>>2) + 4*hf;
        // batch_in_tile = reg>>3, d = (reg&3) + 8*((reg>>2)&1) + 4*hf.
        const int catbase = (layer == 2) ? 128 : ((layer == 0) ? -64 : 0);
        #pragma unroll
        for (int mt = 0; mt < 2; ++mt) {
            const int nb0 = wb0 + mt * 2;
            float cm0 = 0.0f, cm1 = 0.0f;
            #pragma unroll
            for (int nt = 0; nt < 4; ++nt) {
                float r[16];
                #pragma unroll
                for (int reg = 0; reg < 16; ++reg)
                    r[reg] = fmaxf(acc[mt][nt][reg], 0.0f);
                if (layer < 2 && nt < 2) {         // next hidden: cols 0..63
                    const int j = nt * 32 + lane5;
                    #pragma unroll
                    for (int reg = 0; reg < 16; ++reg) {
                        int nb = nb0 + (reg >> 3);
                        int d  = (reg & 3) + 8 * ((reg >> 2) & 1) + 4 * hf;
                        hT[(nb * 16 + d) * 72 + j] = (_Float16)r[reg];
                    }
                }
                if (layer == 2 || nt >= 2) {       // direct-out readout
                    const float w = 1.0f + wnn[catbase + nt * 32 + lane5];
                    float s0 = ((r[0] + r[1]) + (r[2] + r[3])) +
                               ((r[4] + r[5]) + (r[6] + r[7]));
                    float s1 = ((r[8] + r[9]) + (r[10] + r[11])) +
                               ((r[12] + r[13]) + (r[14] + r[15]));
                    s0 += __shfl_xor(s0, 32, 64);  // combine hf halves (full d-sum)
                    s1 += __shfl_xor(s1, 32, 64);
                    cm0 = fmaf(s0, w, cm0);
                    cm1 = fmaf(s1, w, cm1);
                }
            }
            #pragma unroll
            for (int sh = 16; sh >= 1; sh >>= 1) {
                cm0 += __shfl_xor(cm0, sh, 64);
                cm1 += __shfl_xor(cm1, sh, 64);
            }
            if (lane == 0) {
                atomicAdd(&outacc[nb0], cm0);
                atomicAdd(&outacc[nb0 + 1], cm1);
            }
        }
        __syncthreads();   // hT(next hidden) + outacc visible
    }

    if (t < NB) out[b0 + t] = outacc[t] + bnn[0];
}

extern "C" void kernel_launch(void* const* d_in, const int* in_sizes, int n_in,
                              void* d_out, int out_size, void* d_ws, size_t ws_size,
                              hipStream_t stream) {
    const float* xin = (const float*)d_in[0];
    const float* f0g = (const float*)d_in[1];
    const float* f1g = (const float*)d_in[2];
    const float* f2g = (const float*)d_in[3];
    const float* wnn = (const float*)d_in[4];
    const float* bnn = (const float*)d_in[5];
    float* out = (float*)d_out;
    _Float16* fprep = (_Float16*)d_ws;   // 3 * 319488 * 2 B = 1.83 MB

    prep_kernel<<<3 * NC16, 256, 0, stream>>>(f0g, f1g, f2g, fprep);

    const int B = in_sizes[0] / 624;     // 8192
    cin_mfma<<<B / NB, 512, 0, stream>>>(xin, fprep, wnn, bnn, out);
}